// Round 8
// baseline (189.146 us; speedup 1.0000x reference)
//
#include <hip/hip_runtime.h>
#include <cmath>

typedef __bf16 bf16;
typedef bf16 bf16x4 __attribute__((ext_vector_type(4)));
typedef bf16 bf16x8 __attribute__((ext_vector_type(8)));
typedef float f32x4 __attribute__((ext_vector_type(4)));

#define MFMA16(a, b, c) __builtin_amdgcn_mfma_f32_16x16x32_bf16(a, b, c, 0, 0, 0)

// async global->LDS, 16B per lane; LDS dest must be wave-uniform base + lane*16
#define GLOAD16(g, l)                                                   \
  __builtin_amdgcn_global_load_lds(                                     \
      (const __attribute__((address_space(1))) unsigned int*)(g),       \
      (__attribute__((address_space(3))) unsigned int*)(l), 16, 0, 0)

// fp32 -> bf16 bulk convert of x (4Mi), Wqkv (3Mi), Wo (1Mi) in one launch
__global__ __launch_bounds__(256) void cvt_all(
    const float* __restrict__ x, const float* __restrict__ wqkv,
    const float* __restrict__ wo, bf16* __restrict__ xb,
    bf16* __restrict__ wqkvb, bf16* __restrict__ wob) {
  int i = (blockIdx.x * 256 + threadIdx.x) * 4;
  const float* src;
  bf16* dst;
  if (i < (4 << 20)) {
    src = x + i; dst = xb + i;
  } else if (i < (7 << 20)) {
    src = wqkv + (i - (4 << 20)); dst = wqkvb + (i - (4 << 20));
  } else {
    src = wo + (i - (7 << 20)); dst = wob + (i - (7 << 20));
  }
  const f32x4 v = *(const f32x4*)src;
  bf16x4 o = {(bf16)v[0], (bf16)v[1], (bf16)v[2], (bf16)v[3]};
  *(bf16x4*)dst = o;
}

// C[m][n] = sum_k A[m][k] * Bm[n][k]   (NT GEMM, K=1024, 128xBN tile)
// m97 structure: double-buffered LDS, staging via global_load_lds dwordx4,
// one __syncthreads per K-iter.
// T1 XCD swizzle [measured r5/r6: non-attn residual -4us].
// EPI==1 epilogue: sec is BLOCK-uniform (n tiles are 128-aligned):
//   sec<2 : Q or K with RoPE, per-element sincos + direct 2B stores.
//           NOTE r7: these stores are ALREADY dense (16 lanes x 2B = full
//           32B sectors); replacing sincos with a table + LDS repack
//           REGRESSED +10us (dependent gathers + 2 barriers). Keep as-is.
//   sec==2: V^T via LDS transpose: 16B stores [r2: -15us vs 2B scatter]
// EPI==0: plain fp32 store.
template <int EPI, int BN>
__global__ __launch_bounds__(256) void gemm_nt(
    const bf16* __restrict__ A, const bf16* __restrict__ Bm,
    const int* __restrict__ tokpos,
    bf16* __restrict__ out0, bf16* __restrict__ out1, bf16* __restrict__ out2,
    float* __restrict__ outF, int N) {
  constexpr int NI = BN / 32;  // 16x16 acc frags per wave in N
  constexpr int TSTRIDE = 136; // V-transpose tile row stride (272B = 17*16)
  __shared__ __align__(16) union SMem {
    struct { bf16 A[2][128 * 32]; bf16 B[2][BN * 32]; } st;
    bf16 T[EPI ? 128 * TSTRIDE : 1];
  } sm;
  const int tid = threadIdx.x;
  const int w = tid >> 6, lane = tid & 63, quad = lane >> 4, m16 = lane & 15;
  // XCD-aware block swizzle (bijective: nwg multiple of 8)
  const int nwg = gridDim.x * gridDim.y;
  int bid = blockIdx.y * gridDim.x + blockIdx.x;
  bid = (bid & 7) * (nwg >> 3) + (bid >> 3);
  const int m0 = (bid / gridDim.x) * 128, n0 = (bid % gridDim.x) * BN;
  const int wm = (w >> 1) * 64, wn = (w & 1) * (BN / 2);

  f32x4 acc[4][NI] = {};

  const int row0 = tid >> 2, ch = tid & 3;
  const bf16* Ag0 = A + (size_t)(m0 + row0) * 1024 + ch * 8;
  const bf16* Ag1 = Ag0 + (size_t)64 * 1024;
  const bf16* Bg0 = Bm + (size_t)(n0 + row0) * 1024 + ch * 8;
  const bf16* Bg1 = Bg0 + (size_t)64 * 1024;

  auto STAGE = [&](int p, int k0) {
    GLOAD16(Ag0 + k0, &sm.st.A[p][tid * 8]);
    GLOAD16(Ag1 + k0, &sm.st.A[p][2048 + tid * 8]);
    GLOAD16(Bg0 + k0, &sm.st.B[p][tid * 8]);
    if constexpr (BN == 128) GLOAD16(Bg1 + k0, &sm.st.B[p][2048 + tid * 8]);
  };

  STAGE(0, 0);
  __syncthreads();  // vmcnt(0) drain publishes buffer 0

  int p = 0;
  for (int k0 = 0; k0 < 1024; k0 += 32) {
    const bool more = (k0 + 32) < 1024;
    if (more) STAGE(p ^ 1, k0 + 32);  // async into other buffer
    bf16x8 af[4], bfr[NI];
#pragma unroll
    for (int mi = 0; mi < 4; ++mi)
      af[mi] =
          *(const bf16x8*)(&sm.st.A[p][(wm + mi * 16 + m16) * 32 + quad * 8]);
#pragma unroll
    for (int ni = 0; ni < NI; ++ni)
      bfr[ni] =
          *(const bf16x8*)(&sm.st.B[p][(wn + ni * 16 + m16) * 32 + quad * 8]);
#pragma unroll
    for (int mi = 0; mi < 4; ++mi)
#pragma unroll
      for (int ni = 0; ni < NI; ++ni)
        acc[mi][ni] = MFMA16(af[mi], bfr[ni], acc[mi][ni]);
    if (more) {
      __syncthreads();  // single barrier per iter; drains vmcnt+lgkm
      p ^= 1;
    }
  }

  if constexpr (EPI == 0) {
#pragma unroll
    for (int mi = 0; mi < 4; ++mi) {
      int rowb = m0 + wm + mi * 16 + quad * 4;
#pragma unroll
      for (int r = 0; r < 4; ++r) {
        size_t off = (size_t)(rowb + r) * N + n0 + wn;
#pragma unroll
        for (int ni = 0; ni < NI; ++ni)
          outF[off + ni * 16 + m16] = acc[mi][ni][r];
      }
    }
  } else {
    const int secb = n0 >> 10;  // block-uniform: 0=Q 1=K 2=V
    if (secb == 2) {
      // ---- V: LDS-transpose epilogue ----
      __syncthreads();  // all waves done reading staging bufs
#pragma unroll
      for (int mi = 0; mi < 4; ++mi) {
        int rlb = wm + mi * 16 + quad * 4;  // local row (token) 0..127
#pragma unroll
        for (int ni = 0; ni < 4; ++ni) {
          int c = wn + ni * 16 + m16;  // local col (d-dim) 0..127
          bf16x4 pk = {(bf16)acc[mi][ni][0], (bf16)acc[mi][ni][1],
                       (bf16)acc[mi][ni][2], (bf16)acc[mi][ni][3]};
          *(bf16x4*)(&sm.T[c * TSTRIDE + rlb]) = pk;
        }
      }
      __syncthreads();
      const int bb = m0 >> 11, S0 = m0 & 2047;
      const size_t base = ((size_t)bb * 1024 + (n0 - 2048)) * 2048 + S0;
#pragma unroll
      for (int it = 0; it < 8; ++it) {
        int chunk = it * 256 + tid;
        int c = chunk >> 4, kp = (chunk & 15) * 8;
        bf16x8 v = *(const bf16x8*)(&sm.T[c * TSTRIDE + kp]);
        *(bf16x8*)(out2 + base + (size_t)c * 2048 + kp) = v;
      }
    } else {
      // ---- Q or K with RoPE; partner column is lane^1 in same quad ----
      bf16* dst = secb ? out1 : out0;
      const float sc = secb ? 1.0f : 0.125f;  // fold 1/sqrt(64) into Q
#pragma unroll
      for (int mi = 0; mi < 4; ++mi) {
        int rowb = m0 + wm + mi * 16 + quad * 4;
        int pos4[4];
#pragma unroll
        for (int r = 0; r < 4; ++r) pos4[r] = tokpos[rowb + r];
#pragma unroll
        for (int ni = 0; ni < 4; ++ni) {
          int col = n0 + wn + ni * 16 + m16;
          int f = col & 1023, h = f >> 6, d = f & 63;
          float inv = __expf(-(float)(d & ~1) * (9.2103403719762f / 64.f));
#pragma unroll
          for (int r = 0; r < 4; ++r) {
            float v = acc[mi][ni][r];
            float vp = __shfl_xor(v, 1);
            float ang = (float)pos4[r] * inv;
            float cs, sn;
            __sincosf(ang, &sn, &cs);
            float ov = (d & 1) ? (v * cs + vp * sn) : (v * cs - vp * sn);
            ov *= sc;
            int row = rowb + r;
            int bb = row >> 11, s = row & 2047;
            dst[((size_t)(bb * 16 + h) * 2048 + s) * 64 + d] = (bf16)ov;
          }
        }
      }
    }
  }
}

// Causal flash attention, PAIRED q-tiles per block: block (bh, y) owns
// q-tiles jA=y (16..31 rounds... no: jA=y in 0..15) and jB=31-y.
//   - Every block does exactly 33 strip-rounds -> 512 equal blocks = 2/CU,
//     ALL co-resident: no dispatch queue, no drain tail (r6's 1024 variable
//     blocks showed 26% time-avg occupancy vs 50% nominal = idle tail).
//   - Dual strips SHARE the K/V fragment reads: one bk/bv ds_read feeds two
//     MFMAs (halves LDS reads in dual rounds); block count halved also
//     halves K/V staging traffic.
//   - K/V double-buffered via global_load_lds with PRE-SWIZZLED global
//     source (T2/m173): LDS dest linear, source granule c = slot^(row&7),
//     reads XOR the same involution -> conflict-free (r4: 4.2M -> 0).
//   - round kt: issue gload(kt+1) -> QK(kt) -> softmax+PV(kt) -> barrier.
// Fixed-shift softmax p=exp(s-8), Q pre-scaled 1/8.
// Q,K: (bh,s,d).  Vt: (bh,d,s).  O: (b,s,h*64+d) bf16.
__global__ __launch_bounds__(256) void attn_kernel(
    const bf16* __restrict__ Q, const bf16* __restrict__ K,
    const bf16* __restrict__ Vt, bf16* __restrict__ O) {
  __shared__ __align__(16) bf16 KP[2][64 * 64];  // 16KB
  __shared__ __align__(16) bf16 VP[2][64 * 64];  // 16KB
  __shared__ __align__(16) bf16 PS[8][16 * 64];  // 16KB: per-wave x 2 strips
  const int tid = threadIdx.x;
  const int w = tid >> 6, lane = tid & 63, quad = lane >> 4, m16 = lane & 15;
  const int h8 = m16 >> 3, ml = m16 & 7;
  const int bh = blockIdx.x;
  const int jA = blockIdx.y, jB = 31 - jA;  // jA in 0..15 < jB in 16..31
  const bf16* Qb = Q + (size_t)bh * 2048 * 64;
  const bf16* Kb = K + (size_t)bh * 2048 * 64;
  const bf16* Vb = Vt + (size_t)bh * 64 * 2048;

  // staging: thread t fills LDS granules t and 256+t (row t>>3 / +32, slot
  // t&7); global source granule is the XOR-swizzled one: c = slot ^ (row&7).
  const int srow = tid >> 3, sc = (tid & 7) ^ (srow & 7);
  const bf16* Kg = Kb + (size_t)srow * 64 + sc * 8;    // + kt*4096
  const bf16* Vg = Vb + (size_t)srow * 2048 + sc * 8;  // + kt*64
  auto GSTAGE = [&](int kt, int p) {
    const bf16* kg = Kg + (size_t)kt * 4096;
    const bf16* vg = Vg + kt * 64;
    GLOAD16(kg, &KP[p][tid * 8]);
    GLOAD16(kg + (size_t)32 * 64, &KP[p][2048 + tid * 8]);
    GLOAD16(vg, &VP[p][tid * 8]);
    GLOAD16(vg + (size_t)32 * 2048, &VP[p][2048 + tid * 8]);
  };

  // Q strips in A-fragment layout (pre-scaled 1/8), registers for whole block
  const bf16* qrowA = Qb + (size_t)(jA * 64 + w * 16 + m16) * 64;
  const bf16* qrowB = Qb + (size_t)(jB * 64 + w * 16 + m16) * 64;
  bf16x8 aqA[2], aqB[2];
  aqA[0] = *(const bf16x8*)(qrowA + quad * 8);
  aqA[1] = *(const bf16x8*)(qrowA + 32 + quad * 8);
  aqB[0] = *(const bf16x8*)(qrowB + quad * 8);
  aqB[1] = *(const bf16x8*)(qrowB + 32 + quad * 8);

  GSTAGE(0, 0);
  __syncthreads();  // vmcnt(0) drain publishes buffer 0

  f32x4 oA[4] = {}, oB[4] = {};
  float lA[4] = {0.f, 0.f, 0.f, 0.f}, lB[4] = {0.f, 0.f, 0.f, 0.f};
  const int qrel = w * 16 + quad * 4;
  bf16* psA = PS[w];
  bf16* psB = PS[4 + w];

  auto SOFTMAX = [&](const f32x4* sa, float* lp, bf16* ps, bool diag) {
#pragma unroll
    for (int r = 0; r < 4; ++r) {
      const int prow = quad * 4 + r;
      const int rb = prow * 64, rx = prow & 7;
#pragma unroll
      for (int ni = 0; ni < 4; ++ni) {
        // p = exp(s-8) = exp2(s*log2e - 8*log2e)
        float pp = exp2f(fmaf(sa[ni][r], 1.44269504f, -11.5415603f));
        if (diag && (ni * 16 + m16) > qrel + r) pp = 0.f;
        lp[r] += pp;
        ps[rb + (((ni * 2 + h8) ^ rx) << 3) + ml] = (bf16)pp;
      }
    }
  };
  auto READAP = [&](const bf16* ps, bf16x8* ap) {
#pragma unroll
    for (int kk = 0; kk < 2; ++kk)
      ap[kk] =
          *(const bf16x8*)(&ps[m16 * 64 + (((kk * 4 + quad) ^ ml) << 3)]);
  };

  int p = 0;
  for (int kt = 0; kt <= jB; ++kt) {
    const bool more = kt < jB;
    const bool actA = kt <= jA;
    if (more) GSTAGE(kt + 1, p ^ 1);  // async; drained at this round's barrier

    // QK^T: shared bk fragment feeds both strips' MFMAs
    f32x4 saA[4] = {}, saB[4] = {};
    __builtin_amdgcn_s_setprio(1);
    if (actA) {
#pragma unroll
      for (int kk = 0; kk < 2; ++kk)
#pragma unroll
        for (int ni = 0; ni < 4; ++ni) {
          bf16x8 bk = *(const bf16x8*)(
              &KP[p][(ni * 16 + m16) * 64 + (((kk * 4 + quad) ^ ml) << 3)]);
          saB[ni] = MFMA16(aqB[kk], bk, saB[ni]);
          saA[ni] = MFMA16(aqA[kk], bk, saA[ni]);
        }
    } else {
#pragma unroll
      for (int kk = 0; kk < 2; ++kk)
#pragma unroll
        for (int ni = 0; ni < 4; ++ni) {
          bf16x8 bk = *(const bf16x8*)(
              &KP[p][(ni * 16 + m16) * 64 + (((kk * 4 + quad) ^ ml) << 3)]);
          saB[ni] = MFMA16(aqB[kk], bk, saB[ni]);
        }
    }
    __builtin_amdgcn_s_setprio(0);

    SOFTMAX(saB, lB, psB, kt == jB);
    if (actA) SOFTMAX(saA, lA, psA, kt == jA);

    // per-wave strips: intra-wave LDS write->read, no barrier needed
    bf16x8 apA[2], apB[2];
    READAP(psB, apB);
    if (actA) READAP(psA, apA);

    __builtin_amdgcn_s_setprio(1);
    if (actA) {
#pragma unroll
      for (int kk = 0; kk < 2; ++kk)
#pragma unroll
        for (int ng = 0; ng < 4; ++ng) {
          bf16x8 bv = *(const bf16x8*)(
              &VP[p][(ng * 16 + m16) * 64 + (((kk * 4 + quad) ^ ml) << 3)]);
          oB[ng] = MFMA16(apB[kk], bv, oB[ng]);
          oA[ng] = MFMA16(apA[kk], bv, oA[ng]);
        }
    } else {
#pragma unroll
      for (int kk = 0; kk < 2; ++kk)
#pragma unroll
        for (int ng = 0; ng < 4; ++ng) {
          bf16x8 bv = *(const bf16x8*)(
              &VP[p][(ng * 16 + m16) * 64 + (((kk * 4 + quad) ^ ml) << 3)]);
          oB[ng] = MFMA16(apB[kk], bv, oB[ng]);
        }
    }
    __builtin_amdgcn_s_setprio(0);

    if (more) {
      __syncthreads();  // separates rounds + publishes next buffer
      p ^= 1;
    }
  }

  const int b = bh >> 4, hh = bh & 15;
  auto EPI = [&](const f32x4* o, const float* lp, int q0) {
#pragma unroll
    for (int r = 0; r < 4; ++r) {
      float l = lp[r];
      l += __shfl_xor(l, 1);
      l += __shfl_xor(l, 2);
      l += __shfl_xor(l, 4);
      l += __shfl_xor(l, 8);
      float inv_l = 1.f / l;
      int s = q0 + w * 16 + quad * 4 + r;
      size_t rowoff = (size_t)(b * 2048 + s) * 1024 + hh * 64;
#pragma unroll
      for (int ng = 0; ng < 4; ++ng)
        O[rowoff + ng * 16 + m16] = (bf16)(o[ng][r] * inv_l);
    }
  };
  EPI(oA, lA, jA * 64);
  EPI(oB, lB, jB * 64);
}

extern "C" void kernel_launch(void* const* d_in, const int* in_sizes, int n_in,
                              void* d_out, int out_size, void* d_ws, size_t ws_size,
                              hipStream_t stream) {
  (void)in_sizes; (void)n_in; (void)out_size; (void)ws_size;
  const float* x = (const float*)d_in[0];       // (2,2048,1024) fp32
  const float* Wqkv = (const float*)d_in[1];    // (3072,1024) fp32
  const float* Wo = (const float*)d_in[2];      // (1024,1024) fp32
  const int* tokpos = (const int*)d_in[3];      // (2,2048) int32
  float* out = (float*)d_out;                   // (2,2048,1024) fp32

  const size_t NEL = (size_t)2 * 16 * 2048 * 64;  // 4 Mi elements
  bf16* Qws = (bf16*)d_ws;       // (bh, s, d) RoPE + 1/8 scale   8 MiB
  bf16* Kws = Qws + NEL;         // (bh, s, d) with RoPE          8 MiB
  bf16* Vtw = Kws + NEL;         // (bh, d, s)                    8 MiB
  bf16* Ows = Vtw + NEL;         // (b*s, h*64+d)                 8 MiB
  bf16* xb  = Ows + NEL;         // x in bf16                     8 MiB
  bf16* Wqkvb = xb + NEL;        // W_qkv in bf16                 6 MiB
  bf16* Wob = Wqkvb + (size_t)3072 * 1024;  //                    2 MiB

  // 0) fp32 -> bf16 conversion of all inputs (one launch, 8Mi elements)
  cvt_all<<<8192, 256, 0, stream>>>(x, Wqkv, Wo, xb, Wqkvb, Wob);

  // 1) QKV projection + RoPE + head-layout epilogue: M=4096, N=3072
  gemm_nt<1, 128><<<dim3(24, 32), 256, 0, stream>>>(xb, Wqkvb, tokpos, Qws,
                                                    Kws, Vtw, nullptr, 3072);
  // 2) paired-q-tile causal flash attention: 512 equal blocks = 2/CU,
  //    all co-resident (no tail)
  attn_kernel<<<dim3(32, 16), 256, 0, stream>>>(Qws, Kws, Vtw, Ows);
  // 3) output projection: M=4096, N=1024, fp32 output, 64-wide N tile
  gemm_nt<0, 64><<<dim3(16, 32), 256, 0, stream>>>(Ows, Wob, nullptr, nullptr,
                                                   nullptr, nullptr, out, 1024);
}

// Round 9
// 175.617 us; speedup vs baseline: 1.0770x; 1.0770x over previous
//
#include <hip/hip_runtime.h>
#include <cmath>

typedef __bf16 bf16;
typedef bf16 bf16x4 __attribute__((ext_vector_type(4)));
typedef bf16 bf16x8 __attribute__((ext_vector_type(8)));
typedef float f32x4 __attribute__((ext_vector_type(4)));

#define MFMA16(a, b, c) __builtin_amdgcn_mfma_f32_16x16x32_bf16(a, b, c, 0, 0, 0)

// async global->LDS, 16B per lane; LDS dest must be wave-uniform base + lane*16
#define GLOAD16(g, l)                                                   \
  __builtin_amdgcn_global_load_lds(                                     \
      (const __attribute__((address_space(1))) unsigned int*)(g),       \
      (__attribute__((address_space(3))) unsigned int*)(l), 16, 0, 0)

// fp32 -> bf16 bulk convert of x (4Mi), Wqkv (3Mi), Wo (1Mi) in one launch
__global__ __launch_bounds__(256) void cvt_all(
    const float* __restrict__ x, const float* __restrict__ wqkv,
    const float* __restrict__ wo, bf16* __restrict__ xb,
    bf16* __restrict__ wqkvb, bf16* __restrict__ wob) {
  int i = (blockIdx.x * 256 + threadIdx.x) * 4;
  const float* src;
  bf16* dst;
  if (i < (4 << 20)) {
    src = x + i; dst = xb + i;
  } else if (i < (7 << 20)) {
    src = wqkv + (i - (4 << 20)); dst = wqkvb + (i - (4 << 20));
  } else {
    src = wo + (i - (7 << 20)); dst = wob + (i - (7 << 20));
  }
  const f32x4 v = *(const f32x4*)src;
  bf16x4 o = {(bf16)v[0], (bf16)v[1], (bf16)v[2], (bf16)v[3]};
  *(bf16x4*)dst = o;
}

// C[m][n] = sum_k A[m][k] * Bm[n][k]   (NT GEMM, K=1024, 128xBN tile)
// m97 structure: double-buffered LDS, staging via global_load_lds dwordx4,
// one __syncthreads per K-iter.
// T1 XCD swizzle [measured r5/r6: non-attn residual -4us].
// EPI==1 epilogue: sec is BLOCK-uniform (n tiles are 128-aligned):
//   sec<2 : Q or K with RoPE, per-element sincos + direct 2B stores.
//           NOTE r7: these stores are ALREADY dense (16 lanes x 2B = full
//           32B sectors); replacing sincos with a table + LDS repack
//           REGRESSED +10us (dependent gathers + 2 barriers). Keep as-is.
//   sec==2: V^T via LDS transpose: 16B stores [r2: -15us vs 2B scatter]
// EPI==0: plain fp32 store.
template <int EPI, int BN>
__global__ __launch_bounds__(256) void gemm_nt(
    const bf16* __restrict__ A, const bf16* __restrict__ Bm,
    const int* __restrict__ tokpos,
    bf16* __restrict__ out0, bf16* __restrict__ out1, bf16* __restrict__ out2,
    float* __restrict__ outF, int N) {
  constexpr int NI = BN / 32;  // 16x16 acc frags per wave in N
  constexpr int TSTRIDE = 136; // V-transpose tile row stride (272B = 17*16)
  __shared__ __align__(16) union SMem {
    struct { bf16 A[2][128 * 32]; bf16 B[2][BN * 32]; } st;
    bf16 T[EPI ? 128 * TSTRIDE : 1];
  } sm;
  const int tid = threadIdx.x;
  const int w = tid >> 6, lane = tid & 63, quad = lane >> 4, m16 = lane & 15;
  // XCD-aware block swizzle (bijective: nwg multiple of 8)
  const int nwg = gridDim.x * gridDim.y;
  int bid = blockIdx.y * gridDim.x + blockIdx.x;
  bid = (bid & 7) * (nwg >> 3) + (bid >> 3);
  const int m0 = (bid / gridDim.x) * 128, n0 = (bid % gridDim.x) * BN;
  const int wm = (w >> 1) * 64, wn = (w & 1) * (BN / 2);

  f32x4 acc[4][NI] = {};

  const int row0 = tid >> 2, ch = tid & 3;
  const bf16* Ag0 = A + (size_t)(m0 + row0) * 1024 + ch * 8;
  const bf16* Ag1 = Ag0 + (size_t)64 * 1024;
  const bf16* Bg0 = Bm + (size_t)(n0 + row0) * 1024 + ch * 8;
  const bf16* Bg1 = Bg0 + (size_t)64 * 1024;

  auto STAGE = [&](int p, int k0) {
    GLOAD16(Ag0 + k0, &sm.st.A[p][tid * 8]);
    GLOAD16(Ag1 + k0, &sm.st.A[p][2048 + tid * 8]);
    GLOAD16(Bg0 + k0, &sm.st.B[p][tid * 8]);
    if constexpr (BN == 128) GLOAD16(Bg1 + k0, &sm.st.B[p][2048 + tid * 8]);
  };

  STAGE(0, 0);
  __syncthreads();  // vmcnt(0) drain publishes buffer 0

  int p = 0;
  for (int k0 = 0; k0 < 1024; k0 += 32) {
    const bool more = (k0 + 32) < 1024;
    if (more) STAGE(p ^ 1, k0 + 32);  // async into other buffer
    bf16x8 af[4], bfr[NI];
#pragma unroll
    for (int mi = 0; mi < 4; ++mi)
      af[mi] =
          *(const bf16x8*)(&sm.st.A[p][(wm + mi * 16 + m16) * 32 + quad * 8]);
#pragma unroll
    for (int ni = 0; ni < NI; ++ni)
      bfr[ni] =
          *(const bf16x8*)(&sm.st.B[p][(wn + ni * 16 + m16) * 32 + quad * 8]);
#pragma unroll
    for (int mi = 0; mi < 4; ++mi)
#pragma unroll
      for (int ni = 0; ni < NI; ++ni)
        acc[mi][ni] = MFMA16(af[mi], bfr[ni], acc[mi][ni]);
    if (more) {
      __syncthreads();  // single barrier per iter; drains vmcnt+lgkm
      p ^= 1;
    }
  }

  if constexpr (EPI == 0) {
#pragma unroll
    for (int mi = 0; mi < 4; ++mi) {
      int rowb = m0 + wm + mi * 16 + quad * 4;
#pragma unroll
      for (int r = 0; r < 4; ++r) {
        size_t off = (size_t)(rowb + r) * N + n0 + wn;
#pragma unroll
        for (int ni = 0; ni < NI; ++ni)
          outF[off + ni * 16 + m16] = acc[mi][ni][r];
      }
    }
  } else {
    const int secb = n0 >> 10;  // block-uniform: 0=Q 1=K 2=V
    if (secb == 2) {
      // ---- V: LDS-transpose epilogue ----
      __syncthreads();  // all waves done reading staging bufs
#pragma unroll
      for (int mi = 0; mi < 4; ++mi) {
        int rlb = wm + mi * 16 + quad * 4;  // local row (token) 0..127
#pragma unroll
        for (int ni = 0; ni < 4; ++ni) {
          int c = wn + ni * 16 + m16;  // local col (d-dim) 0..127
          bf16x4 pk = {(bf16)acc[mi][ni][0], (bf16)acc[mi][ni][1],
                       (bf16)acc[mi][ni][2], (bf16)acc[mi][ni][3]};
          *(bf16x4*)(&sm.T[c * TSTRIDE + rlb]) = pk;
        }
      }
      __syncthreads();
      const int bb = m0 >> 11, S0 = m0 & 2047;
      const size_t base = ((size_t)bb * 1024 + (n0 - 2048)) * 2048 + S0;
#pragma unroll
      for (int it = 0; it < 8; ++it) {
        int chunk = it * 256 + tid;
        int c = chunk >> 4, kp = (chunk & 15) * 8;
        bf16x8 v = *(const bf16x8*)(&sm.T[c * TSTRIDE + kp]);
        *(bf16x8*)(out2 + base + (size_t)c * 2048 + kp) = v;
      }
    } else {
      // ---- Q or K with RoPE; partner column is lane^1 in same quad ----
      bf16* dst = secb ? out1 : out0;
      const float sc = secb ? 1.0f : 0.125f;  // fold 1/sqrt(64) into Q
#pragma unroll
      for (int mi = 0; mi < 4; ++mi) {
        int rowb = m0 + wm + mi * 16 + quad * 4;
        int pos4[4];
#pragma unroll
        for (int r = 0; r < 4; ++r) pos4[r] = tokpos[rowb + r];
#pragma unroll
        for (int ni = 0; ni < 4; ++ni) {
          int col = n0 + wn + ni * 16 + m16;
          int f = col & 1023, h = f >> 6, d = f & 63;
          float inv = __expf(-(float)(d & ~1) * (9.2103403719762f / 64.f));
#pragma unroll
          for (int r = 0; r < 4; ++r) {
            float v = acc[mi][ni][r];
            float vp = __shfl_xor(v, 1);
            float ang = (float)pos4[r] * inv;
            float cs, sn;
            __sincosf(ang, &sn, &cs);
            float ov = (d & 1) ? (v * cs + vp * sn) : (v * cs - vp * sn);
            ov *= sc;
            int row = rowb + r;
            int bb = row >> 11, s = row & 2047;
            dst[((size_t)(bb * 16 + h) * 2048 + s) * 64 + d] = (bf16)ov;
          }
        }
      }
    }
  }
}

// Causal flash attention, one 64-row q-tile per block, 1024 blocks dispatched
// longest-first (LPT under HW backfill: proven r4/r6; "balanced" static maps
// and q-tile pairing both REGRESSED -- r5: +10us, r8: +13us. Do not repack
// work; add resident contexts instead).
// r9: SINGLE-buffered K and V (LDS 40KB -> 24KB => 6 blocks/CU, was 4) with a
// split 2-barrier pipeline replacing the second buffer:
//   round kt: QK(KP) -> B1 (KP free; drains V(kt) load) -> issue K(kt+1)
//             -> softmax+PV(VP) -> B2 (VP free; drains K(kt+1)) -> issue V(kt+1)
// Every gload still issues one phase ahead and is drained by an existing
// barrier's vmcnt(0); K-load hides under softmax+PV, V-load under next QK.
// Rationale: r6 counters showed VALU issue totals ~23us of the 52us kernel
// at 45% VALUBusy / 26% occupancy -- latency-bound, needs more waves.
//   - K/V staged via global_load_lds with PRE-SWIZZLED global source
//     (T2/m173): LDS dest linear, source granule c = slot^(row&7), reads
//     XOR the same involution -> conflict-free (r4: 4.2M -> 0).
// Fixed-shift softmax p=exp(s-8), Q pre-scaled 1/8.
// Q,K: (bh,s,d).  Vt: (bh,d,s).  O: (b,s,h*64+d) bf16.
__global__ __launch_bounds__(256) void attn_kernel(
    const bf16* __restrict__ Q, const bf16* __restrict__ K,
    const bf16* __restrict__ Vt, bf16* __restrict__ O) {
  __shared__ __align__(16) bf16 KP[64 * 64];     // 8KB, single buffer
  __shared__ __align__(16) bf16 VP[64 * 64];     // 8KB, single buffer
  __shared__ __align__(16) bf16 PS[4][16 * 64];  // 8KB, per-wave P strip
  const int tid = threadIdx.x;
  const int w = tid >> 6, lane = tid & 63, quad = lane >> 4, m16 = lane & 15;
  const int h8 = m16 >> 3, ml = m16 & 7;
  const int bh = blockIdx.x;
  const int j = 31 - blockIdx.y;  // longest q-tiles dispatched first (LPT)
  const bf16* Qb = Q + (size_t)bh * 2048 * 64;
  const bf16* Kb = K + (size_t)bh * 2048 * 64;
  const bf16* Vb = Vt + (size_t)bh * 64 * 2048;

  // staging: thread t fills LDS granules t and 256+t (row t>>3 / +32, slot
  // t&7); global source granule is the XOR-swizzled one: c = slot ^ (row&7).
  const int srow = tid >> 3, sc = (tid & 7) ^ (srow & 7);
  const bf16* Kg = Kb + (size_t)srow * 64 + sc * 8;    // + kt*4096
  const bf16* Vg = Vb + (size_t)srow * 2048 + sc * 8;  // + kt*64
  auto GK = [&](int kt) {
    const bf16* kg = Kg + (size_t)kt * 4096;
    GLOAD16(kg, &KP[tid * 8]);
    GLOAD16(kg + (size_t)32 * 64, &KP[2048 + tid * 8]);
  };
  auto GV = [&](int kt) {
    const bf16* vg = Vg + kt * 64;
    GLOAD16(vg, &VP[tid * 8]);
    GLOAD16(vg + (size_t)32 * 2048, &VP[2048 + tid * 8]);
  };

  // Q strip (rows j*64 + w*16 + m16) in A-fragment layout (pre-scaled 1/8)
  const bf16* qrow = Qb + (size_t)(j * 64 + w * 16 + m16) * 64;
  bf16x8 aq[2];
  aq[0] = *(const bf16x8*)(qrow + quad * 8);
  aq[1] = *(const bf16x8*)(qrow + 32 + quad * 8);

  GK(0);
  GV(0);
  __syncthreads();  // vmcnt(0) drain publishes K(0), V(0)

  f32x4 o[4] = {};
  float l4[4] = {0.f, 0.f, 0.f, 0.f};
  const int qrel = w * 16 + quad * 4;
  bf16* ps = PS[w];

  for (int kt = 0; kt <= j; ++kt) {
    const bool more = kt < j;

    // QK^T against KP (swizzled granules: conflict-free ds_read_b128)
    f32x4 sa[4] = {};
    __builtin_amdgcn_s_setprio(1);
#pragma unroll
    for (int kk = 0; kk < 2; ++kk)
#pragma unroll
      for (int ni = 0; ni < 4; ++ni) {
        bf16x8 bk = *(const bf16x8*)(
            &KP[(ni * 16 + m16) * 64 + (((kk * 4 + quad) ^ ml) << 3)]);
        sa[ni] = MFMA16(aq[kk], bk, sa[ni]);
      }
    __builtin_amdgcn_s_setprio(0);

    __syncthreads();   // B1: KP free for overwrite; drains V(kt) load
    if (more) GK(kt + 1);  // async; hides under softmax+PV; drained at B2

    // fixed-shift softmax + swizzled P strip
    const bool diag = (kt == j);
#pragma unroll
    for (int r = 0; r < 4; ++r) {
      const int prow = quad * 4 + r;
      const int rb = prow * 64, rx = prow & 7;
#pragma unroll
      for (int ni = 0; ni < 4; ++ni) {
        // p = exp(s-8) = exp2(s*log2e - 8*log2e)
        float pp = exp2f(fmaf(sa[ni][r], 1.44269504f, -11.5415603f));
        if (diag && (ni * 16 + m16) > qrel + r) pp = 0.f;
        l4[r] += pp;
        ps[rb + (((ni * 2 + h8) ^ rx) << 3) + ml] = (bf16)pp;
      }
    }
    // per-wave strip: intra-wave LDS write->read, no barrier needed
    bf16x8 ap[2];
#pragma unroll
    for (int kk = 0; kk < 2; ++kk)
      ap[kk] =
          *(const bf16x8*)(&ps[m16 * 64 + (((kk * 4 + quad) ^ ml) << 3)]);
    __builtin_amdgcn_s_setprio(1);
#pragma unroll
    for (int kk = 0; kk < 2; ++kk)
#pragma unroll
      for (int ng = 0; ng < 4; ++ng) {
        bf16x8 bv = *(const bf16x8*)(
            &VP[(ng * 16 + m16) * 64 + (((kk * 4 + quad) ^ ml) << 3)]);
        o[ng] = MFMA16(ap[kk], bv, o[ng]);
      }
    __builtin_amdgcn_s_setprio(0);

    if (more) {
      __syncthreads();  // B2: VP free; K(kt+1) drained -> ready for next QK
      GV(kt + 1);       // async; hides under next round's QK; drained at B1
    }
  }

  const int b = bh >> 4, hh = bh & 15;
#pragma unroll
  for (int r = 0; r < 4; ++r) {
    float l = l4[r];
    l += __shfl_xor(l, 1);
    l += __shfl_xor(l, 2);
    l += __shfl_xor(l, 4);
    l += __shfl_xor(l, 8);
    float inv_l = 1.f / l;
    int s = j * 64 + w * 16 + quad * 4 + r;
    size_t rowoff = (size_t)(b * 2048 + s) * 1024 + hh * 64;
#pragma unroll
    for (int ng = 0; ng < 4; ++ng)
      O[rowoff + ng * 16 + m16] = (bf16)(o[ng][r] * inv_l);
  }
}

extern "C" void kernel_launch(void* const* d_in, const int* in_sizes, int n_in,
                              void* d_out, int out_size, void* d_ws, size_t ws_size,
                              hipStream_t stream) {
  (void)in_sizes; (void)n_in; (void)out_size; (void)ws_size;
  const float* x = (const float*)d_in[0];       // (2,2048,1024) fp32
  const float* Wqkv = (const float*)d_in[1];    // (3072,1024) fp32
  const float* Wo = (const float*)d_in[2];      // (1024,1024) fp32
  const int* tokpos = (const int*)d_in[3];      // (2,2048) int32
  float* out = (float*)d_out;                   // (2,2048,1024) fp32

  const size_t NEL = (size_t)2 * 16 * 2048 * 64;  // 4 Mi elements
  bf16* Qws = (bf16*)d_ws;       // (bh, s, d) RoPE + 1/8 scale   8 MiB
  bf16* Kws = Qws + NEL;         // (bh, s, d) with RoPE          8 MiB
  bf16* Vtw = Kws + NEL;         // (bh, d, s)                    8 MiB
  bf16* Ows = Vtw + NEL;         // (b*s, h*64+d)                 8 MiB
  bf16* xb  = Ows + NEL;         // x in bf16                     8 MiB
  bf16* Wqkvb = xb + NEL;        // W_qkv in bf16                 6 MiB
  bf16* Wob = Wqkvb + (size_t)3072 * 1024;  //                    2 MiB

  // 0) fp32 -> bf16 conversion of all inputs (one launch, 8Mi elements)
  cvt_all<<<8192, 256, 0, stream>>>(x, Wqkv, Wo, xb, Wqkvb, Wob);

  // 1) QKV projection + RoPE + head-layout epilogue: M=4096, N=3072
  gemm_nt<1, 128><<<dim3(24, 32), 256, 0, stream>>>(xb, Wqkvb, tokpos, Qws,
                                                    Kws, Vtw, nullptr, 3072);
  // 2) causal flash attention, one q-tile per block (1024 blocks, LPT order,
  //    24KB LDS -> 6 blocks/CU)
  attn_kernel<<<dim3(32, 32), 256, 0, stream>>>(Qws, Kws, Vtw, Ows);
  // 3) output projection: M=4096, N=1024, fp32 output, 64-wide N tile
  gemm_nt<0, 64><<<dim3(16, 32), 256, 0, stream>>>(Ows, Wob, nullptr, nullptr,
                                                   nullptr, nullptr, out, 1024);
}